// Round 8
// baseline (272.662 us; speedup 1.0000x reference)
//
#include <hip/hip_runtime.h>
#include <hip/hip_bf16.h>

// Shapes: B=4, N=2048, M=2048, DIM=512, HEADS=8, DIM_HEAD=64, HIDDEN=512

typedef __attribute__((ext_vector_type(8))) short bf16x8;   // 8 bf16 = 4 VGPRs (MFMA A/B frag)
typedef __attribute__((ext_vector_type(4))) float f32x4;    // MFMA C/D frag

#define MFMA16(a, b, c) __builtin_amdgcn_mfma_f32_16x16x32_bf16(a, b, c, 0, 0, 0)
#define SCALE_LOG2E 0.18033688011112042f   // DIM_HEAD^-0.5 * log2(e)

static __device__ inline unsigned short f2b(float f) {
    __hip_bfloat16 h = __float2bfloat16(f);
    return __builtin_bit_cast(unsigned short, h);
}
// round-to-nearest (bits +0x8000) and pack two f32 -> (bf16(hi)<<16)|bf16(lo)
static __device__ inline unsigned int pk_rnd(float hi, float lo) {
    unsigned uh = __builtin_bit_cast(unsigned, hi) + 0x8000u;
    unsigned ul = __builtin_bit_cast(unsigned, lo) + 0x8000u;
    return __builtin_amdgcn_perm(uh, ul, 0x07060302);
}
// async global->LDS DMA, 16B per lane; lds base must be wave-uniform
static __device__ inline void gll16(const void* g, void* l) {
    __builtin_amdgcn_global_load_lds(
        (const __attribute__((address_space(1))) void*)g,
        (__attribute__((address_space(3))) void*)l, 16, 0, 0);
}

// ---------------- prep: cvt x, cvt ctx, transpose weights — one kernel ---------
// flat grid 8448: [0,4096) cvt x, [4096,8192) cvt ctx, [8192,8448) transw.
__global__ __launch_bounds__(256) void prep_kernel(const float* __restrict__ x,
                                                   const float* __restrict__ ctx,
                                                   const float* __restrict__ Wq,
                                                   const float* __restrict__ Wk,
                                                   const float* __restrict__ Wv,
                                                   const float* __restrict__ Wo,
                                                   unsigned short* __restrict__ xb,
                                                   unsigned short* __restrict__ cb,
                                                   unsigned short* __restrict__ wt_base) {
    __shared__ float T[64][65];
    const int bid = blockIdx.x, tid = threadIdx.x;
    if (bid < 8192) {
        const float* src = (bid < 4096) ? x : ctx;
        unsigned short* dst = (bid < 4096) ? xb : cb;
        int i = (bid & 4095) * 256 + tid;
        const float4 v = reinterpret_cast<const float4*>(src)[i];
        uint2 o;
        o.x = pk_rnd(v.y, v.x);
        o.y = pk_rnd(v.w, v.z);
        reinterpret_cast<uint2*>(dst)[i] = o;
        return;
    }
    const int b = bid - 8192;               // [0,256)
    const int which = b >> 6, t6 = b & 63;
    const float* W = (which == 0) ? Wq : (which == 1) ? Wk : (which == 2) ? Wv : Wo;
    unsigned short* Wt = wt_base + (size_t)which * 512 * 512;
    const int n0 = (t6 & 7) * 64, k0 = (t6 >> 3) * 64;
    const int rr = tid >> 4, cc = (tid & 15) * 4;
    #pragma unroll
    for (int i = 0; i < 4; i++) {
        const float4 v = *reinterpret_cast<const float4*>(&W[(size_t)(k0 + rr + 16 * i) * 512 + n0 + cc]);
        T[rr + 16 * i][cc + 0] = v.x; T[rr + 16 * i][cc + 1] = v.y;
        T[rr + 16 * i][cc + 2] = v.z; T[rr + 16 * i][cc + 3] = v.w;
    }
    __syncthreads();
    #pragma unroll
    for (int i = 0; i < 4; i++) {
        int n = rr + 16 * i;
        uint2 o;
        o.x = pk_rnd(T[cc + 1][n], T[cc + 0][n]);
        o.y = pk_rnd(T[cc + 3][n], T[cc + 2][n]);
        *reinterpret_cast<uint2*>(&Wt[(size_t)(n0 + n) * 512 + k0 + cc]) = o;
    }
}

// ---------------- GEMM core: 128x128 tile at (row0,col0), BK=32, 4 waves -------
// XOR-swizzled global_load_lds staging: LDS[row][q]=G[row][q^(row&3)],
// frag reads un-swizzle with quad^(m&3).
__device__ inline void gemm_tile_128(const unsigned short* __restrict__ A,
                                     const unsigned short* __restrict__ Bt,
                                     int row0, int col0, f32x4 acc[4][4]) {
    __shared__ unsigned short As[128 * 32];
    __shared__ unsigned short Bs[128 * 32];
    const int tid  = threadIdx.x;
    const int lane = tid & 63, wave = tid >> 6;
    const int quad = lane >> 4, mr = lane & 15;
    const int m_off = (wave & 1) * 64, n_off = (wave >> 1) * 64;

    const int lrow = lane >> 2;                 // 0..15 local row
    const int lq   = (lane & 3) ^ (lrow & 3);   // swizzled source quarter
    const unsigned short* aSrc = A  + (size_t)(row0 + wave * 32 + lrow) * 512 + lq * 8;
    const unsigned short* bSrc = Bt + (size_t)(col0 + wave * 32 + lrow) * 512 + lq * 8;
    unsigned short* aL0 = &As[(wave * 32) * 32];
    unsigned short* aL1 = &As[(wave * 32 + 16) * 32];
    unsigned short* bL0 = &Bs[(wave * 32) * 32];
    unsigned short* bL1 = &Bs[(wave * 32 + 16) * 32];

    for (int kt = 0; kt < 16; kt++) {
        __syncthreads();
        gll16(aSrc + kt * 32, aL0);
        gll16(aSrc + 16 * 512 + kt * 32, aL1);
        gll16(bSrc + kt * 32, bL0);
        gll16(bSrc + 16 * 512 + kt * 32, bL1);
        __syncthreads();
        bf16x8 af[4], bfr[4];
        #pragma unroll
        for (int i = 0; i < 4; i++) {
            int m = m_off + i * 16 + mr;
            af[i] = *reinterpret_cast<const bf16x8*>(&As[m * 32 + ((quad ^ (m & 3)) * 8)]);
        }
        #pragma unroll
        for (int j = 0; j < 4; j++) {
            int n = n_off + j * 16 + mr;
            bfr[j] = *reinterpret_cast<const bf16x8*>(&Bs[n * 32 + ((quad ^ (n & 3)) * 8)]);
        }
        #pragma unroll
        for (int i = 0; i < 4; i++)
            #pragma unroll
            for (int j = 0; j < 4; j++)
                acc[i][j] = MFMA16(af[i], bfr[j], acc[i][j]);
    }
}

// ---------------- QKV projection GEMM ----------------
// flat grid 768, XCD-swizzled.
__global__ __launch_bounds__(256) void gemm_proj_kernel(const unsigned short* __restrict__ xb,
                                                        const unsigned short* __restrict__ cb,
                                                        const unsigned short* __restrict__ wt_base,
                                                        unsigned short* __restrict__ qkv_base) {
    const int f = blockIdx.x, g = f & 7, j = f >> 3;
    const int xt = j & 3;                 // col tile [0,4)
    const int ry = g + 8 * ((j >> 2) & 7);// row tile [0,64)
    const int which = j >> 5;             // 0 Q, 1 K, 2 V

    const unsigned short* A  = (which == 0) ? xb : cb;
    const unsigned short* Bt = wt_base + (size_t)which * 512 * 512;
    unsigned short* out      = qkv_base + (size_t)which * 8192 * 512;

    f32x4 acc[4][4];
    #pragma unroll
    for (int i = 0; i < 4; i++)
        #pragma unroll
        for (int j2 = 0; j2 < 4; j2++) acc[i][j2] = (f32x4){0.f, 0.f, 0.f, 0.f};

    gemm_tile_128(A, Bt, ry * 128, xt * 128, acc);

    const int lane = threadIdx.x & 63, wave = threadIdx.x >> 6;
    const int quad = lane >> 4, mr = lane & 15;
    const int m_off = (wave & 1) * 64, n_off = (wave >> 1) * 64;
    const float qs = (which == 0) ? SCALE_LOG2E : 1.0f;

    if (which == 2) {
        // V^T: out[(b*8+h)*64 + d][n] — r-values are consecutive n: pack uint2
        #pragma unroll
        for (int i = 0; i < 4; i++) {
            #pragma unroll
            for (int j2 = 0; j2 < 4; j2++) {
                int gcol = xt * 128 + n_off + j2 * 16 + mr;
                int h = gcol >> 6, d = gcol & 63;
                int grow = ry * 128 + m_off + i * 16 + quad * 4;
                int b = grow >> 11, n = grow & 2047;
                uint2 o;
                o.x = pk_rnd(acc[i][j2][1], acc[i][j2][0]);
                o.y = pk_rnd(acc[i][j2][3], acc[i][j2][2]);
                *reinterpret_cast<uint2*>(&out[((size_t)(b * 8 + h) * 64 + d) * 2048 + n]) = o;
            }
        }
    } else {
        #pragma unroll
        for (int i = 0; i < 4; i++) {
            #pragma unroll
            for (int j2 = 0; j2 < 4; j2++) {
                int gcol = xt * 128 + n_off + j2 * 16 + mr;
                int h = gcol >> 6, d = gcol & 63;
                #pragma unroll
                for (int r = 0; r < 4; r++) {
                    int grow = ry * 128 + m_off + i * 16 + quad * 4 + r;
                    int b = grow >> 11, n = grow & 2047;
                    out[((size_t)(b * 8 + h) * 2048 + n) * 64 + d] = f2b(acc[i][j2][r] * qs);
                }
            }
        }
    }
}

// ---------------- flash attention, barrier-free (S^T, max-free softmax) --------
// flat grid 1024 x 256 thr = 4 waves; wave owns 32 q-rows x 1024 keys (ksplit=2).
// K/V fragments are loaded DIRECTLY from global (L2-resident after XCD swizzle,
// FETCH=12MB proves it): the 4 quads of one mr cover a full 64B line, so the
// loads are line-coalesced. P round-trip stays wave-private in LDS (lgkmcnt
// wait only). ZERO __syncthreads -> no vmcnt(0) barrier drains; waves slide
// freely (m114 overlap). l = P*ones MFMA; Q pre-scaled by scale*log2e.
__global__ __launch_bounds__(256, 4) void flash_kernel(const unsigned short* __restrict__ qw,
                                                       const unsigned short* __restrict__ kw,
                                                       const unsigned short* __restrict__ vt,
                                                       float* __restrict__ p0,
                                                       float* __restrict__ p1,
                                                       float* __restrict__ l0,
                                                       float* __restrict__ l1) {
    __shared__ unsigned short Pw[4][32 * 72];   // per-wave P[qlocal][key]

    const int f = blockIdx.x, g = f & 7, j = f >> 3;
    const int qtile = j & 15;                   // [0,16): 128-q tile
    const int kidx  = (j >> 4) & 1;             // key half
    const int bh    = g + 8 * (j >> 5);         // [0,32)

    const int tid  = threadIdx.x;
    const int lane = tid & 63, wave = tid >> 6;
    const int quad = lane >> 4, mr = lane & 15;

    const unsigned short* qbase = qw + ((size_t)bh * 2048 + qtile * 128 + wave * 32) * 64;
    // per-lane K/V bases: K row = key (mr-indexed), V row = d (mr-indexed)
    const unsigned short* kL = kw + (size_t)bh * 2048 * 64 + (size_t)mr * 64 + quad * 8;
    const unsigned short* vL = vt + (size_t)bh * 64 * 2048 + (size_t)mr * 2048 + quad * 8;
    float* Pdst = kidx ? p1 : p0;
    float* ldst = kidx ? l1 : l0;

    // Q fragments, B-operand layout: B[n=qlocal][k=c*32+quad*8+jj]. Pre-scaled.
    bf16x8 qf[2][2];
    #pragma unroll
    for (int gq = 0; gq < 2; gq++) {
        qf[gq][0] = *reinterpret_cast<const bf16x8*>(qbase + (gq * 16 + mr) * 64 + quad * 8);
        qf[gq][1] = *reinterpret_cast<const bf16x8*>(qbase + (gq * 16 + mr) * 64 + 32 + quad * 8);
    }

    bf16x8 ones;
    #pragma unroll
    for (int e = 0; e < 8; e++) ones[e] = (short)0x3F80;   // bf16 1.0

    f32x4 oacc[2][4], lacc[2];
    #pragma unroll
    for (int gq = 0; gq < 2; gq++) {
        lacc[gq] = (f32x4){0.f, 0.f, 0.f, 0.f};
        #pragma unroll
        for (int nt = 0; nt < 4; nt++) oacc[gq][nt] = (f32x4){0.f, 0.f, 0.f, 0.f};
    }

    const int kbeg = kidx * 1024;
    for (int key0 = kbeg; key0 < kbeg + 1024; key0 += 64) {
        // K fragments direct from global: kf[c][kt] = K[key0+kt*16+mr][c*32+quad*8..]
        bf16x8 kf[2][4];
        #pragma unroll
        for (int c = 0; c < 2; c++)
            #pragma unroll
            for (int kt = 0; kt < 4; kt++)
                kf[c][kt] = *reinterpret_cast<const bf16x8*>(kL + (size_t)(key0 + kt * 16) * 64 + c * 32);

        // V fragments direct from global: vf[ks][nt] = V^T[nt*16+mr][key0+ks*32+quad*8..]
        // (issued now so the L2 latency hides under QK MFMA + exp2 VALU)
        bf16x8 vf[2][4];
        #pragma unroll
        for (int ks = 0; ks < 2; ks++)
            #pragma unroll
            for (int nt = 0; nt < 4; nt++)
                vf[ks][nt] = *reinterpret_cast<const bf16x8*>(vL + (size_t)nt * 16 * 2048 + key0 + ks * 32);

        // S^T = K·Q^T : per q-group, C rows = key (kt*16+quad*4+r), cols = qrow (mr)
        f32x4 sv[2][4];
        #pragma unroll
        for (int gq = 0; gq < 2; gq++)
            #pragma unroll
            for (int kt = 0; kt < 4; kt++) sv[gq][kt] = (f32x4){0.f, 0.f, 0.f, 0.f};
        #pragma unroll
        for (int c = 0; c < 2; c++) {
            #pragma unroll
            for (int kt = 0; kt < 4; kt++) {
                sv[0][kt] = MFMA16(kf[c][kt], qf[0][c], sv[0][kt]);
                sv[1][kt] = MFMA16(kf[c][kt], qf[1][c], sv[1][kt]);
            }
        }

        // p = exp2(s); cheap-round pack; write P — ds_write_b64, wave-private
        #pragma unroll
        for (int gq = 0; gq < 2; gq++) {
            #pragma unroll
            for (int kt = 0; kt < 4; kt++) {
                uint2 w;
                w.x = pk_rnd(__builtin_exp2f(sv[gq][kt][1]), __builtin_exp2f(sv[gq][kt][0]));
                w.y = pk_rnd(__builtin_exp2f(sv[gq][kt][3]), __builtin_exp2f(sv[gq][kt][2]));
                *reinterpret_cast<uint2*>(&Pw[wave][(gq * 16 + mr) * 72 + kt * 16 + quad * 4]) = w;
            }
        }
        asm volatile("s_waitcnt lgkmcnt(0)" ::: "memory");  // wave-local P visibility

        // O += P·V ; l += P·1
        #pragma unroll
        for (int ks = 0; ks < 2; ks++) {
            bf16x8 pf0 = *reinterpret_cast<const bf16x8*>(&Pw[wave][(mr) * 72 + ks * 32 + quad * 8]);
            bf16x8 pf1 = *reinterpret_cast<const bf16x8*>(&Pw[wave][(16 + mr) * 72 + ks * 32 + quad * 8]);
            lacc[0] = MFMA16(pf0, ones, lacc[0]);
            lacc[1] = MFMA16(pf1, ones, lacc[1]);
            #pragma unroll
            for (int nt = 0; nt < 4; nt++) {
                oacc[0][nt] = MFMA16(pf0, vf[ks][nt], oacc[0][nt]);
                oacc[1][nt] = MFMA16(pf1, vf[ks][nt], oacc[1][nt]);
            }
        }
    }

    // epilogue: partial O (fp32, unnormalized) at [b][n][h*64+d]; partial l
    const int b = bh >> 3, h = bh & 7;
    #pragma unroll
    for (int gq = 0; gq < 2; gq++) {
        #pragma unroll
        for (int nt = 0; nt < 4; nt++) {
            #pragma unroll
            for (int r = 0; r < 4; r++) {
                int row = qtile * 128 + wave * 32 + gq * 16 + quad * 4 + r;
                Pdst[((size_t)b * 2048 + row) * 512 + h * 64 + nt * 16 + mr] = oacc[gq][nt][r];
            }
        }
        if (mr == 0) {
            #pragma unroll
            for (int r = 0; r < 4; r++) {
                int row = qtile * 128 + wave * 32 + gq * 16 + quad * 4 + r;
                ldst[(size_t)bh * 2048 + row] = lacc[gq][r];
            }
        }
    }
}

// ---------------- combine: ob = bf16((P0+P1)/(l0+l1)) ----------------
// grid 4096 x 256; thread handles 4 consecutive fp32 (one float4) -> ushort4.
__global__ __launch_bounds__(256) void combine_kernel(const float* __restrict__ p0,
                                                      const float* __restrict__ p1,
                                                      const float* __restrict__ l0,
                                                      const float* __restrict__ l1,
                                                      unsigned short* __restrict__ ob) {
    const int idx = blockIdx.x * 256 + threadIdx.x;      // [0, 1048576)
    const size_t flat = (size_t)idx * 4;                 // element index
    const int row = (int)(flat >> 9);                    // b*2048+n in [0,8192)
    const int c   = (int)(flat & 511);
    const int bh  = (row >> 11) * 8 + (c >> 6);
    const int qn  = row & 2047;
    const float lv = l0[(size_t)bh * 2048 + qn] + l1[(size_t)bh * 2048 + qn];
    const float li = 1.0f / lv;
    const float4 a = reinterpret_cast<const float4*>(p0)[idx];
    const float4 bb = reinterpret_cast<const float4*>(p1)[idx];
    uint2 o;
    o.x = pk_rnd((a.y + bb.y) * li, (a.x + bb.x) * li);
    o.y = pk_rnd((a.w + bb.w) * li, (a.z + bb.z) * li);
    reinterpret_cast<uint2*>(ob)[idx] = o;
}

// ---------------- output projection GEMM (+bias, fp32 out) ----------------
// flat grid 256, XCD-swizzled like proj.
__global__ __launch_bounds__(256) void gemm_out_kernel(const unsigned short* __restrict__ obuf,
                                                       const unsigned short* __restrict__ Wot,
                                                       const float* __restrict__ bo,
                                                       float* __restrict__ out) {
    const int f = blockIdx.x, g = f & 7, j = f >> 3;
    const int xt = j & 3;                  // col tile
    const int ry = g + 8 * (j >> 2);       // row tile [0,64)

    f32x4 acc[4][4];
    #pragma unroll
    for (int i = 0; i < 4; i++)
        #pragma unroll
        for (int j2 = 0; j2 < 4; j2++) acc[i][j2] = (f32x4){0.f, 0.f, 0.f, 0.f};

    gemm_tile_128(obuf, Wot, ry * 128, xt * 128, acc);

    const int lane = threadIdx.x & 63, wave = threadIdx.x >> 6;
    const int quad = lane >> 4, mr = lane & 15;
    const int m_off = (wave & 1) * 64, n_off = (wave >> 1) * 64;
    #pragma unroll
    for (int i = 0; i < 4; i++) {
        #pragma unroll
        for (int j2 = 0; j2 < 4; j2++) {
            int gcol = xt * 128 + n_off + j2 * 16 + mr;
            float bias = bo[gcol];
            #pragma unroll
            for (int r = 0; r < 4; r++) {
                int grow = ry * 128 + m_off + i * 16 + quad * 4 + r;
                out[(size_t)grow * 512 + gcol] = acc[i][j2][r] + bias;
            }
        }
    }
}

extern "C" void kernel_launch(void* const* d_in, const int* in_sizes, int n_in,
                              void* d_out, int out_size, void* d_ws, size_t ws_size,
                              hipStream_t stream) {
    const float* x   = (const float*)d_in[0];
    const float* ctx = (const float*)d_in[1];
    const float* Wq  = (const float*)d_in[2];
    const float* Wk  = (const float*)d_in[3];
    const float* Wv  = (const float*)d_in[4];
    const float* Wo  = (const float*)d_in[5];
    const float* bo  = (const float*)d_in[6];
    float* out = (float*)d_out;

    unsigned short* ws  = (unsigned short*)d_ws;
    unsigned short* xb  = ws;                                  // 8192*512   (dead after proj -> flash partial-1)
    unsigned short* cb  = xb + (size_t)8192 * 512;             // 8192*512   (dead after proj -> flash partial-1)
    unsigned short* Wt  = cb + (size_t)8192 * 512;             // 4 * 512*512 (slots 0,1 dead after proj -> l0,l1)
    unsigned short* qkv = Wt + (size_t)4 * 512 * 512;          // 3 * 8192*512
    unsigned short* ob  = qkv + (size_t)3 * 8192 * 512;        // 8192*512

    float* p0 = out;                       // d_out as scratch; overwritten by gemm_out
    float* p1 = (float*)xb;                // 4.19M floats over xb+cb (8.39M ushorts)
    float* l0 = (float*)Wt;                // 64K floats over Wq^T slot
    float* l1 = (float*)(Wt + (size_t)512 * 512);   // over Wk^T slot

    prep_kernel<<<8448, 256, 0, stream>>>(x, ctx, Wq, Wk, Wv, Wo, xb, cb, Wt);
    gemm_proj_kernel<<<768, 256, 0, stream>>>(xb, cb, Wt, qkv);
    flash_kernel<<<1024, 256, 0, stream>>>(qkv, qkv + (size_t)8192 * 512,
                                           qkv + (size_t)2 * 8192 * 512, p0, p1, l0, l1);
    combine_kernel<<<4096, 256, 0, stream>>>(p0, p1, l0, l1, ob);
    gemm_out_kernel<<<256, 256, 0, stream>>>(ob, Wt + (size_t)3 * 512 * 512, bo, out);
}

// Round 9
// 188.568 us; speedup vs baseline: 1.4460x; 1.4460x over previous
//
#include <hip/hip_runtime.h>
#include <hip/hip_bf16.h>

// Shapes: B=4, N=2048, M=2048, DIM=512, HEADS=8, DIM_HEAD=64, HIDDEN=512

typedef __attribute__((ext_vector_type(8))) short bf16x8;   // 8 bf16 = 4 VGPRs (MFMA A/B frag)
typedef __attribute__((ext_vector_type(4))) float f32x4;    // MFMA C/D frag

#define MFMA16(a, b, c) __builtin_amdgcn_mfma_f32_16x16x32_bf16(a, b, c, 0, 0, 0)
#define SCALE_LOG2E 0.18033688011112042f   // DIM_HEAD^-0.5 * log2(e)

static __device__ inline unsigned short f2b(float f) {
    __hip_bfloat16 h = __float2bfloat16(f);
    return __builtin_bit_cast(unsigned short, h);
}
// round-to-nearest (bits +0x8000) and pack two f32 -> (bf16(hi)<<16)|bf16(lo)
static __device__ inline unsigned int pk_rnd(float hi, float lo) {
    unsigned uh = __builtin_bit_cast(unsigned, hi) + 0x8000u;
    unsigned ul = __builtin_bit_cast(unsigned, lo) + 0x8000u;
    return __builtin_amdgcn_perm(uh, ul, 0x07060302);
}
// raw v_exp_f32: args are bounded (|x|<~5, outputs 2^-5..2^5) so the ocml
// denormal-range expansion (~4 extra VALU/call) is pure waste. 1 inst, 1/4 rate.
static __device__ inline float fexp2(float x) {
    float r;
    asm("v_exp_f32 %0, %1" : "=v"(r) : "v"(x));
    return r;
}
// async global->LDS DMA, 16B per lane; lds base must be wave-uniform
static __device__ inline void gll16(const void* g, void* l) {
    __builtin_amdgcn_global_load_lds(
        (const __attribute__((address_space(1))) void*)g,
        (__attribute__((address_space(3))) void*)l, 16, 0, 0);
}

// ---------------- prep: cvt x, cvt ctx, transpose weights — one kernel ---------
// flat grid 8448: [0,4096) cvt x, [4096,8192) cvt ctx, [8192,8448) transw.
__global__ __launch_bounds__(256) void prep_kernel(const float* __restrict__ x,
                                                   const float* __restrict__ ctx,
                                                   const float* __restrict__ Wq,
                                                   const float* __restrict__ Wk,
                                                   const float* __restrict__ Wv,
                                                   const float* __restrict__ Wo,
                                                   unsigned short* __restrict__ xb,
                                                   unsigned short* __restrict__ cb,
                                                   unsigned short* __restrict__ wt_base) {
    __shared__ float T[64][65];
    const int bid = blockIdx.x, tid = threadIdx.x;
    if (bid < 8192) {
        const float* src = (bid < 4096) ? x : ctx;
        unsigned short* dst = (bid < 4096) ? xb : cb;
        int i = (bid & 4095) * 256 + tid;
        const float4 v = reinterpret_cast<const float4*>(src)[i];
        uint2 o;
        o.x = pk_rnd(v.y, v.x);
        o.y = pk_rnd(v.w, v.z);
        reinterpret_cast<uint2*>(dst)[i] = o;
        return;
    }
    const int b = bid - 8192;               // [0,256)
    const int which = b >> 6, t6 = b & 63;
    const float* W = (which == 0) ? Wq : (which == 1) ? Wk : (which == 2) ? Wv : Wo;
    unsigned short* Wt = wt_base + (size_t)which * 512 * 512;
    const int n0 = (t6 & 7) * 64, k0 = (t6 >> 3) * 64;
    const int rr = tid >> 4, cc = (tid & 15) * 4;
    #pragma unroll
    for (int i = 0; i < 4; i++) {
        const float4 v = *reinterpret_cast<const float4*>(&W[(size_t)(k0 + rr + 16 * i) * 512 + n0 + cc]);
        T[rr + 16 * i][cc + 0] = v.x; T[rr + 16 * i][cc + 1] = v.y;
        T[rr + 16 * i][cc + 2] = v.z; T[rr + 16 * i][cc + 3] = v.w;
    }
    __syncthreads();
    #pragma unroll
    for (int i = 0; i < 4; i++) {
        int n = rr + 16 * i;
        uint2 o;
        o.x = pk_rnd(T[cc + 1][n], T[cc + 0][n]);
        o.y = pk_rnd(T[cc + 3][n], T[cc + 2][n]);
        *reinterpret_cast<uint2*>(&Wt[(size_t)(n0 + n) * 512 + k0 + cc]) = o;
    }
}

// ---------------- GEMM core: 128x128 tile at (row0,col0), BK=32, 4 waves -------
// XOR-swizzled global_load_lds staging: LDS[row][q]=G[row][q^(row&3)],
// frag reads un-swizzle with quad^(m&3).
__device__ inline void gemm_tile_128(const unsigned short* __restrict__ A,
                                     const unsigned short* __restrict__ Bt,
                                     int row0, int col0, f32x4 acc[4][4]) {
    __shared__ unsigned short As[128 * 32];
    __shared__ unsigned short Bs[128 * 32];
    const int tid  = threadIdx.x;
    const int lane = tid & 63, wave = tid >> 6;
    const int quad = lane >> 4, mr = lane & 15;
    const int m_off = (wave & 1) * 64, n_off = (wave >> 1) * 64;

    const int lrow = lane >> 2;                 // 0..15 local row
    const int lq   = (lane & 3) ^ (lrow & 3);   // swizzled source quarter
    const unsigned short* aSrc = A  + (size_t)(row0 + wave * 32 + lrow) * 512 + lq * 8;
    const unsigned short* bSrc = Bt + (size_t)(col0 + wave * 32 + lrow) * 512 + lq * 8;
    unsigned short* aL0 = &As[(wave * 32) * 32];
    unsigned short* aL1 = &As[(wave * 32 + 16) * 32];
    unsigned short* bL0 = &Bs[(wave * 32) * 32];
    unsigned short* bL1 = &Bs[(wave * 32 + 16) * 32];

    for (int kt = 0; kt < 16; kt++) {
        __syncthreads();
        gll16(aSrc + kt * 32, aL0);
        gll16(aSrc + 16 * 512 + kt * 32, aL1);
        gll16(bSrc + kt * 32, bL0);
        gll16(bSrc + 16 * 512 + kt * 32, bL1);
        __syncthreads();
        bf16x8 af[4], bfr[4];
        #pragma unroll
        for (int i = 0; i < 4; i++) {
            int m = m_off + i * 16 + mr;
            af[i] = *reinterpret_cast<const bf16x8*>(&As[m * 32 + ((quad ^ (m & 3)) * 8)]);
        }
        #pragma unroll
        for (int j = 0; j < 4; j++) {
            int n = n_off + j * 16 + mr;
            bfr[j] = *reinterpret_cast<const bf16x8*>(&Bs[n * 32 + ((quad ^ (n & 3)) * 8)]);
        }
        #pragma unroll
        for (int i = 0; i < 4; i++)
            #pragma unroll
            for (int j = 0; j < 4; j++)
                acc[i][j] = MFMA16(af[i], bfr[j], acc[i][j]);
    }
}

// ---------------- QKV projection GEMM ----------------
// flat grid 768, XCD-swizzled.
__global__ __launch_bounds__(256) void gemm_proj_kernel(const unsigned short* __restrict__ xb,
                                                        const unsigned short* __restrict__ cb,
                                                        const unsigned short* __restrict__ wt_base,
                                                        unsigned short* __restrict__ qkv_base) {
    const int f = blockIdx.x, g = f & 7, j = f >> 3;
    const int xt = j & 3;                 // col tile [0,4)
    const int ry = g + 8 * ((j >> 2) & 7);// row tile [0,64)
    const int which = j >> 5;             // 0 Q, 1 K, 2 V

    const unsigned short* A  = (which == 0) ? xb : cb;
    const unsigned short* Bt = wt_base + (size_t)which * 512 * 512;
    unsigned short* out      = qkv_base + (size_t)which * 8192 * 512;

    f32x4 acc[4][4];
    #pragma unroll
    for (int i = 0; i < 4; i++)
        #pragma unroll
        for (int j2 = 0; j2 < 4; j2++) acc[i][j2] = (f32x4){0.f, 0.f, 0.f, 0.f};

    gemm_tile_128(A, Bt, ry * 128, xt * 128, acc);

    const int lane = threadIdx.x & 63, wave = threadIdx.x >> 6;
    const int quad = lane >> 4, mr = lane & 15;
    const int m_off = (wave & 1) * 64, n_off = (wave >> 1) * 64;
    const float qs = (which == 0) ? SCALE_LOG2E : 1.0f;

    if (which == 2) {
        // V^T: out[(b*8+h)*64 + d][n] — r-values are consecutive n: pack uint2
        #pragma unroll
        for (int i = 0; i < 4; i++) {
            #pragma unroll
            for (int j2 = 0; j2 < 4; j2++) {
                int gcol = xt * 128 + n_off + j2 * 16 + mr;
                int h = gcol >> 6, d = gcol & 63;
                int grow = ry * 128 + m_off + i * 16 + quad * 4;
                int b = grow >> 11, n = grow & 2047;
                uint2 o;
                o.x = pk_rnd(acc[i][j2][1], acc[i][j2][0]);
                o.y = pk_rnd(acc[i][j2][3], acc[i][j2][2]);
                *reinterpret_cast<uint2*>(&out[((size_t)(b * 8 + h) * 64 + d) * 2048 + n]) = o;
            }
        }
    } else {
        #pragma unroll
        for (int i = 0; i < 4; i++) {
            #pragma unroll
            for (int j2 = 0; j2 < 4; j2++) {
                int gcol = xt * 128 + n_off + j2 * 16 + mr;
                int h = gcol >> 6, d = gcol & 63;
                #pragma unroll
                for (int r = 0; r < 4; r++) {
                    int grow = ry * 128 + m_off + i * 16 + quad * 4 + r;
                    int b = grow >> 11, n = grow & 2047;
                    out[((size_t)(b * 8 + h) * 2048 + n) * 64 + d] = f2b(acc[i][j2][r] * qs);
                }
            }
        }
    }
}

// ---------------- flash attention, key-split (S^T, max-free softmax) -----------
// flat grid 1024 x 256 thr = 4 waves; wave owns 32 q-rows; block owns 128 q-rows
// x 1024 keys (ksplit=2). LDS-staged K/V (r7 structure — direct-global r8
// variant was 2x WORSE: unamortized L2 traffic + unpipelined load latency).
// Max-free softmax: partials combine as (O0+O1)/(l0+l1), no max-rescale.
__global__ __launch_bounds__(256) void flash_kernel(const unsigned short* __restrict__ qw,
                                                    const unsigned short* __restrict__ kw,
                                                    const unsigned short* __restrict__ vt,
                                                    float* __restrict__ p0,
                                                    float* __restrict__ p1,
                                                    float* __restrict__ l0,
                                                    float* __restrict__ l1) {
    __shared__ unsigned short Ks[64 * 72];      // [key][d]
    __shared__ unsigned short Vs[64 * 72];      // [d][key]  (V^T tile)
    __shared__ unsigned short Pw[4][32 * 72];   // per-wave P[qlocal][key]

    const int f = blockIdx.x, g = f & 7, j = f >> 3;
    const int qtile = j & 15;                   // [0,16): 128-q tile
    const int kidx  = (j >> 4) & 1;             // key half
    const int bh    = g + 8 * (j >> 5);         // [0,32)

    const int tid  = threadIdx.x;
    const int lane = tid & 63, wave = tid >> 6;
    const int quad = lane >> 4, mr = lane & 15;

    const unsigned short* qbase = qw + ((size_t)bh * 2048 + qtile * 128 + wave * 32) * 64;
    const unsigned short* kbase = kw + (size_t)bh * 2048 * 64;
    const unsigned short* vbase = vt + (size_t)bh * 64 * 2048;
    float* Pdst = kidx ? p1 : p0;
    float* ldst = kidx ? l1 : l0;

    // Q fragments, B-operand layout: B[n=qlocal][k=c*32+quad*8+jj]. Pre-scaled.
    bf16x8 qf[2][2];
    #pragma unroll
    for (int gq = 0; gq < 2; gq++) {
        qf[gq][0] = *reinterpret_cast<const bf16x8*>(qbase + (gq * 16 + mr) * 64 + quad * 8);
        qf[gq][1] = *reinterpret_cast<const bf16x8*>(qbase + (gq * 16 + mr) * 64 + 32 + quad * 8);
    }

    bf16x8 ones;
    #pragma unroll
    for (int e = 0; e < 8; e++) ones[e] = (short)0x3F80;   // bf16 1.0

    f32x4 oacc[2][4], lacc[2];
    #pragma unroll
    for (int gq = 0; gq < 2; gq++) {
        lacc[gq] = (f32x4){0.f, 0.f, 0.f, 0.f};
        #pragma unroll
        for (int nt = 0; nt < 4; nt++) oacc[gq][nt] = (f32x4){0.f, 0.f, 0.f, 0.f};
    }

    // staging with 256 thr: each thread covers 16 contiguous ushorts (2x uint4)
    const int srow = tid >> 2, soff = (tid & 3) * 16;

    const int kbeg = kidx * 1024;
    for (int key0 = kbeg; key0 < kbeg + 1024; key0 += 64) {
        __syncthreads();
        {   // stage K [64 keys][64 d] and V^T [64 d][64 keys]
            const uint4* kp = reinterpret_cast<const uint4*>(kbase + (size_t)(key0 + srow) * 64 + soff);
            uint4* kd = reinterpret_cast<uint4*>(&Ks[srow * 72 + soff]);
            kd[0] = kp[0]; kd[1] = kp[1];
            const uint4* vp = reinterpret_cast<const uint4*>(vbase + (size_t)srow * 2048 + key0 + soff);
            uint4* vd = reinterpret_cast<uint4*>(&Vs[srow * 72 + soff]);
            vd[0] = vp[0]; vd[1] = vp[1];
        }
        __syncthreads();

        // S^T = K·Q^T : per q-group, C rows = key (kt*16+quad*4+r), cols = qrow (mr)
        f32x4 sv[2][4];
        #pragma unroll
        for (int gq = 0; gq < 2; gq++)
            #pragma unroll
            for (int kt = 0; kt < 4; kt++) sv[gq][kt] = (f32x4){0.f, 0.f, 0.f, 0.f};
        #pragma unroll
        for (int c = 0; c < 2; c++) {
            #pragma unroll
            for (int kt = 0; kt < 4; kt++) {
                bf16x8 kf = *reinterpret_cast<const bf16x8*>(&Ks[(kt * 16 + mr) * 72 + c * 32 + quad * 8]);
                sv[0][kt] = MFMA16(kf, qf[0][c], sv[0][kt]);
                sv[1][kt] = MFMA16(kf, qf[1][c], sv[1][kt]);
            }
        }

        // p = exp2(s) via raw v_exp_f32; cheap-round pack; write P — ds_write_b64
        #pragma unroll
        for (int gq = 0; gq < 2; gq++) {
            #pragma unroll
            for (int kt = 0; kt < 4; kt++) {
                uint2 w;
                w.x = pk_rnd(fexp2(sv[gq][kt][1]), fexp2(sv[gq][kt][0]));
                w.y = pk_rnd(fexp2(sv[gq][kt][3]), fexp2(sv[gq][kt][2]));
                *reinterpret_cast<uint2*>(&Pw[wave][(gq * 16 + mr) * 72 + kt * 16 + quad * 4]) = w;
            }
        }
        asm volatile("s_waitcnt lgkmcnt(0)" ::: "memory");  // wave-local P visibility

        // O += P·V ; l += P·1 — V-frags read once, shared across both q-groups
        #pragma unroll
        for (int ks = 0; ks < 2; ks++) {
            bf16x8 pf0 = *reinterpret_cast<const bf16x8*>(&Pw[wave][(mr) * 72 + ks * 32 + quad * 8]);
            bf16x8 pf1 = *reinterpret_cast<const bf16x8*>(&Pw[wave][(16 + mr) * 72 + ks * 32 + quad * 8]);
            lacc[0] = MFMA16(pf0, ones, lacc[0]);
            lacc[1] = MFMA16(pf1, ones, lacc[1]);
            #pragma unroll
            for (int nt = 0; nt < 4; nt++) {
                bf16x8 vf = *reinterpret_cast<const bf16x8*>(&Vs[(nt * 16 + mr) * 72 + ks * 32 + quad * 8]);
                oacc[0][nt] = MFMA16(pf0, vf, oacc[0][nt]);
                oacc[1][nt] = MFMA16(pf1, vf, oacc[1][nt]);
            }
        }
    }

    // epilogue: partial O (fp32, unnormalized) at [b][n][h*64+d]; partial l
    const int b = bh >> 3, h = bh & 7;
    #pragma unroll
    for (int gq = 0; gq < 2; gq++) {
        #pragma unroll
        for (int nt = 0; nt < 4; nt++) {
            #pragma unroll
            for (int r = 0; r < 4; r++) {
                int row = qtile * 128 + wave * 32 + gq * 16 + quad * 4 + r;
                Pdst[((size_t)b * 2048 + row) * 512 + h * 64 + nt * 16 + mr] = oacc[gq][nt][r];
            }
        }
        if (mr == 0) {
            #pragma unroll
            for (int r = 0; r < 4; r++) {
                int row = qtile * 128 + wave * 32 + gq * 16 + quad * 4 + r;
                ldst[(size_t)bh * 2048 + row] = lacc[gq][r];
            }
        }
    }
}

// ---------------- combine: ob = bf16((P0+P1)/(l0+l1)) ----------------
// grid 4096 x 256; thread handles 4 consecutive fp32 (one float4) -> ushort4.
__global__ __launch_bounds__(256) void combine_kernel(const float* __restrict__ p0,
                                                      const float* __restrict__ p1,
                                                      const float* __restrict__ l0,
                                                      const float* __restrict__ l1,
                                                      unsigned short* __restrict__ ob) {
    const int idx = blockIdx.x * 256 + threadIdx.x;      // [0, 1048576)
    const size_t flat = (size_t)idx * 4;                 // element index
    const int row = (int)(flat >> 9);                    // b*2048+n in [0,8192)
    const int c   = (int)(flat & 511);
    const int bh  = (row >> 11) * 8 + (c >> 6);
    const int qn  = row & 2047;
    const float lv = l0[(size_t)bh * 2048 + qn] + l1[(size_t)bh * 2048 + qn];
    const float li = 1.0f / lv;
    const float4 a = reinterpret_cast<const float4*>(p0)[idx];
    const float4 bb = reinterpret_cast<const float4*>(p1)[idx];
    uint2 o;
    o.x = pk_rnd((a.y + bb.y) * li, (a.x + bb.x) * li);
    o.y = pk_rnd((a.w + bb.w) * li, (a.z + bb.z) * li);
    reinterpret_cast<uint2*>(ob)[idx] = o;
}

// ---------------- output projection GEMM (+bias, fp32 out) ----------------
// flat grid 256, XCD-swizzled like proj.
__global__ __launch_bounds__(256) void gemm_out_kernel(const unsigned short* __restrict__ obuf,
                                                       const unsigned short* __restrict__ Wot,
                                                       const float* __restrict__ bo,
                                                       float* __restrict__ out) {
    const int f = blockIdx.x, g = f & 7, j = f >> 3;
    const int xt = j & 3;                  // col tile
    const int ry = g + 8 * (j >> 2);       // row tile [0,64)

    f32x4 acc[4][4];
    #pragma unroll
    for (int i = 0; i < 4; i++)
        #pragma unroll
        for (int j2 = 0; j2 < 4; j2++) acc[i][j2] = (f32x4){0.f, 0.f, 0.f, 0.f};

    gemm_tile_128(obuf, Wot, ry * 128, xt * 128, acc);

    const int lane = threadIdx.x & 63, wave = threadIdx.x >> 6;
    const int quad = lane >> 4, mr = lane & 15;
    const int m_off = (wave & 1) * 64, n_off = (wave >> 1) * 64;
    #pragma unroll
    for (int i = 0; i < 4; i++) {
        #pragma unroll
        for (int j2 = 0; j2 < 4; j2++) {
            int gcol = xt * 128 + n_off + j2 * 16 + mr;
            float bias = bo[gcol];
            #pragma unroll
            for (int r = 0; r < 4; r++) {
                int grow = ry * 128 + m_off + i * 16 + quad * 4 + r;
                out[(size_t)grow * 512 + gcol] = acc[i][j2][r] + bias;
            }
        }
    }
}

extern "C" void kernel_launch(void* const* d_in, const int* in_sizes, int n_in,
                              void* d_out, int out_size, void* d_ws, size_t ws_size,
                              hipStream_t stream) {
    const float* x   = (const float*)d_in[0];
    const float* ctx = (const float*)d_in[1];
    const float* Wq  = (const float*)d_in[2];
    const float* Wk  = (const float*)d_in[3];
    const float* Wv  = (const float*)d_in[4];
    const float* Wo  = (const float*)d_in[5];
    const float* bo  = (const float*)d_in[6];
    float* out = (float*)d_out;

    unsigned short* ws  = (unsigned short*)d_ws;
    unsigned short* xb  = ws;                                  // 8192*512   (dead after proj -> flash partial-1)
    unsigned short* cb  = xb + (size_t)8192 * 512;             // 8192*512   (dead after proj -> flash partial-1)
    unsigned short* Wt  = cb + (size_t)8192 * 512;             // 4 * 512*512 (slots 0,1 dead after proj -> l0,l1)
    unsigned short* qkv = Wt + (size_t)4 * 512 * 512;          // 3 * 8192*512
    unsigned short* ob  = qkv + (size_t)3 * 8192 * 512;        // 8192*512

    float* p0 = out;                       // d_out as scratch; overwritten by gemm_out
    float* p1 = (float*)xb;                // 4.19M floats over xb+cb (8.39M ushorts)
    float* l0 = (float*)Wt;                // 64K floats over Wq^T slot
    float* l1 = (float*)(Wt + (size_t)512 * 512);   // over Wk^T slot

    prep_kernel<<<8448, 256, 0, stream>>>(x, ctx, Wq, Wk, Wv, Wo, xb, cb, Wt);
    gemm_proj_kernel<<<768, 256, 0, stream>>>(xb, cb, Wt, qkv);
    flash_kernel<<<1024, 256, 0, stream>>>(qkv, qkv + (size_t)8192 * 512,
                                           qkv + (size_t)2 * 8192 * 512, p0, p1, l0, l1);
    combine_kernel<<<4096, 256, 0, stream>>>(p0, p1, l0, l1, ob);
    gemm_out_kernel<<<256, 256, 0, stream>>>(ob, Wt + (size_t)3 * 512 * 512, bo, out);
}